// Round 6
// baseline (201.021 us; speedup 1.0000x reference)
//
#include <hip/hip_runtime.h>

// FixedActionDecoder: sims = (X/||x||) @ (A/||a||cols); segment-max over
// ACTION_INDEX=[0,0,0,0,1,1,1,1,1,2,3]; argmax; one-hot.
// Row-norm of X is argmax-invariant -> skipped.
//
// r6 = r4 base (passing, 88.6us) with the LDS pipe unthrottled:
//  - R=4 rows/lane (256-row wave tiles): the 176 W-broadcast b128s per tile
//    amortize over 2x rows -> 8.25 cyc/row (r4: 16.5, co-limiting with HBM).
//  - Quarter-row staging with T14 async split: issue next quarter's 16
//    global_load_dwordx4 to REGISTERS early, commit to LDS after a full
//    compute-quarter has hidden HBM latency. vmcnt(0) only after cover.
//  - Single wave-private LDS buffer (DS pipe is in-order per wave: the
//    overwrite is safe after the reads have issued); row stride 20 dwords
//    (16 data + 4 pad) gives balanced banks (8 dw/bank) on both phases.
//  - 43.8 KB LDS/block -> 3 blocks/CU = 6 waves/CU (r5's 4 was too few).
// Numerics identical to r4: f32 pass + gap<TAU flags via __ballot ->
// f64 repair of ~1e3 rows (r1/r2-validated). W/bits live in __device__
// globals (r3 lesson: nothing shares d_ws).

#define NP 11
#define TAU 1e-3f
#define QS 20  // quarter-buffer row stride in dwords (16 data + 4 pad)

__device__ __align__(16) float g_W32[704];      // [(d>>2)*44 + (d&3)*11 + p]
__device__ double g_W64[704];                   // [d*11 + p]
__device__ unsigned long long g_bits[1 << 20];  // near-tie flags, 1 bit/row

__global__ void prep(const float* __restrict__ A) {
    int p = threadIdx.x;
    if (p < NP) {
        double ss = 0.0;
        for (int d = 0; d < 64; ++d) { double v = (double)A[d * NP + p]; ss += v * v; }
        double sc = 1.0 / fmax(sqrt(ss), 1e-8);
        for (int d = 0; d < 64; ++d) {
            double w = (double)A[d * NP + p] * sc;
            g_W64[d * NP + p] = w;
            g_W32[(d >> 2) * 44 + (d & 3) * NP + p] = (float)w;
        }
    }
}

__device__ __forceinline__ void argmax_gap(const float* s, int& idx, float& gap) {
    // Segment max per ACTION_INDEX = [0,0,0,0, 1,1,1,1,1, 2, 3]
    float m0 = fmaxf(fmaxf(s[0], s[1]), fmaxf(s[2], s[3]));
    float m1 = fmaxf(fmaxf(fmaxf(s[4], s[5]), s[6]), fmaxf(s[7], s[8]));
    float m2 = s[9], m3 = s[10];
    idx = 0; float best = m0;
    if (m1 > best) { best = m1; idx = 1; }
    if (m2 > best) { best = m2; idx = 2; }
    if (m3 > best) { best = m3; idx = 3; }
    float second = -3.4e38f;
    if (idx != 0) second = fmaxf(second, m0);
    if (idx != 1) second = fmaxf(second, m1);
    if (idx != 2) second = fmaxf(second, m2);
    if (idx != 3) second = fmaxf(second, m3);
    gap = best - second;
}

__global__ __launch_bounds__(128) void decode(const float* __restrict__ X,
                                              float* __restrict__ out, int B) {
    __shared__ float xq[2][256][QS];  // 2 waves x 20480 B, wave-private
    __shared__ float w_lds[704];      // 2816 B, block-shared

    const int tid = threadIdx.x;
    const int lane = tid & 63;
    const int wv = tid >> 6;
    float(*buf)[QS] = xq[wv];

    for (int t = tid; t < 176; t += 128)
        reinterpret_cast<float4*>(w_lds)[t] =
            reinterpret_cast<const float4*>(g_W32)[t];
    __syncthreads();

    const float4* X4 = reinterpret_cast<const float4*>(X);
    const int gwave = blockIdx.x * 2 + wv;
    const int stride = gridDim.x * 2 * 256;
    const int base0 = gwave * 256;
    if (base0 >= B) return;

    const int srow = lane >> 2;  // staging row sub-index (0..15)
    const int sf = lane & 3;     // staging float4 index within quarter

    float4 st[16];  // in-flight quarter: 16 rows/instr x 16 instrs = 256 rows

    // Prologue: issue tile0/quarter0 (cold stall once).
    #pragma unroll
    for (int i = 0; i < 16; ++i) {
        int r = base0 + i * 16 + srow;
        if (r >= B) r = B - 1;  // tail clamp: dup read, never stored
        st[i] = X4[(size_t)r * 16 + sf];
    }

    #pragma unroll 1
    for (int base = base0; base < B; base += stride) {
        const int next = base + stride;

        float acc[4][NP];
        #pragma unroll
        for (int j = 0; j < 4; ++j)
            #pragma unroll
            for (int p = 0; p < NP; ++p) acc[j][p] = 0.0f;

        #pragma unroll 1
        for (int q = 0; q < 4; ++q) {
            // Commit staged quarter to LDS (loads issued a full compute
            // quarter ago -> vmcnt(0) is latency-covered, not a stall).
            asm volatile("s_waitcnt vmcnt(0)" ::: "memory");
            __builtin_amdgcn_sched_barrier(0);
            #pragma unroll
            for (int i = 0; i < 16; ++i)
                *reinterpret_cast<float4*>(&buf[i * 16 + srow][sf * 4]) = st[i];
            __builtin_amdgcn_wave_barrier();
            __builtin_amdgcn_sched_barrier(0);

            // T14: issue next quarter's loads before computing this one.
            int nq = q + 1, nbase = base;
            if (nq == 4) { nq = 0; nbase = next; }
            if (nbase < B) {
                #pragma unroll
                for (int i = 0; i < 16; ++i) {
                    int r = nbase + i * 16 + srow;
                    if (r >= B) r = B - 1;
                    st[i] = X4[(size_t)r * 16 + nq * 4 + sf];
                }
            }

            // Compute quarter q. Per chunk: 11 W-broadcast b128 + 4 lane
            // b128 (rows lane+64j, stride-20 -> balanced banks) + 176 fma.
            // unroll 1: W never bulk-hoisted (r2 lesson).
            #pragma unroll 1
            for (int kk = 0; kk < 4; ++kk) {
                const float* wrow = &w_lds[(q * 4 + kk) * 44];
                float4 x0 = *reinterpret_cast<const float4*>(&buf[lane][kk * 4]);
                float4 x1 = *reinterpret_cast<const float4*>(&buf[lane + 64][kk * 4]);
                float4 x2 = *reinterpret_cast<const float4*>(&buf[lane + 128][kk * 4]);
                float4 x3 = *reinterpret_cast<const float4*>(&buf[lane + 192][kk * 4]);
                #pragma unroll
                for (int p = 0; p < NP; ++p) {
                    float w0 = wrow[p], w1 = wrow[NP + p];
                    float w2 = wrow[2 * NP + p], w3 = wrow[3 * NP + p];
                    float t;
                    t = fmaf(x0.x, w0, acc[0][p]); t = fmaf(x0.y, w1, t);
                    t = fmaf(x0.z, w2, t);         acc[0][p] = fmaf(x0.w, w3, t);
                    t = fmaf(x1.x, w0, acc[1][p]); t = fmaf(x1.y, w1, t);
                    t = fmaf(x1.z, w2, t);         acc[1][p] = fmaf(x1.w, w3, t);
                    t = fmaf(x2.x, w0, acc[2][p]); t = fmaf(x2.y, w1, t);
                    t = fmaf(x2.z, w2, t);         acc[2][p] = fmaf(x2.w, w3, t);
                    t = fmaf(x3.x, w0, acc[3][p]); t = fmaf(x3.y, w1, t);
                    t = fmaf(x3.z, w2, t);         acc[3][p] = fmaf(x3.w, w3, t);
                }
            }
            __builtin_amdgcn_wave_barrier();
        }

        // Epilogue: argmax + flag + one-hot store (register-only).
        #pragma unroll
        for (int j = 0; j < 4; ++j) {
            int idx; float gap;
            argmax_gap(acc[j], idx, gap);
            unsigned long long m = __ballot(gap < TAU);
            if (lane == 0) g_bits[(base >> 6) + j] = m;
            int r = base + j * 64 + lane;
            if (r < B) {
                float4 o;
                o.x = (idx == 0) ? 1.0f : 0.0f;
                o.y = (idx == 1) ? 1.0f : 0.0f;
                o.z = (idx == 2) ? 1.0f : 0.0f;
                o.w = (idx == 3) ? 1.0f : 0.0f;
                reinterpret_cast<float4*>(out)[r] = o;
            }
        }
    }
}

__global__ __launch_bounds__(256) void repair(const float* __restrict__ X,
                                              float* __restrict__ out, int B) {
    const int nwords = (B + 63) >> 6;
    for (int t = blockIdx.x * blockDim.x + threadIdx.x; t < nwords;
         t += gridDim.x * blockDim.x) {
        unsigned long long m = g_bits[t];
        while (m) {
            int b = __builtin_ctzll(m);
            m &= m - 1;
            int row = t * 64 + b;
            if (row >= B) continue;

            double s[NP];
            #pragma unroll
            for (int p = 0; p < NP; ++p) s[p] = 0.0;
            #pragma unroll 1
            for (int d = 0; d < 64; ++d) {
                double x = (double)X[(size_t)row * 64 + d];
                #pragma unroll
                for (int p = 0; p < NP; ++p)
                    s[p] = fma(x, g_W64[d * NP + p], s[p]);
            }

            double m0 = fmax(fmax(s[0], s[1]), fmax(s[2], s[3]));
            double m1 = fmax(fmax(fmax(s[4], s[5]), s[6]), fmax(s[7], s[8]));
            double m2 = s[9], m3 = s[10];
            int idx = 0; double best = m0;
            if (m1 > best) { best = m1; idx = 1; }
            if (m2 > best) { best = m2; idx = 2; }
            if (m3 > best) { best = m3; idx = 3; }

            float4 o;
            o.x = (idx == 0) ? 1.0f : 0.0f;
            o.y = (idx == 1) ? 1.0f : 0.0f;
            o.z = (idx == 2) ? 1.0f : 0.0f;
            o.w = (idx == 3) ? 1.0f : 0.0f;
            reinterpret_cast<float4*>(out)[row] = o;
        }
    }
}

extern "C" void kernel_launch(void* const* d_in, const int* in_sizes, int n_in,
                              void* d_out, int out_size, void* d_ws, size_t ws_size,
                              hipStream_t stream) {
    const float* X = (const float*)d_in[0];
    const float* A = (const float*)d_in[1];
    float* out = (float*)d_out;
    const int B = in_sizes[0] / 64;

    hipLaunchKernelGGL(prep, dim3(1), dim3(64), 0, stream, A);
    hipLaunchKernelGGL(decode, dim3(768), dim3(128), 0, stream, X, out, B);
    hipLaunchKernelGGL(repair, dim3(128), dim3(256), 0, stream, X, out, B);
}

// Round 7
// 149.206 us; speedup vs baseline: 1.3473x; 1.3473x over previous
//
#include <hip/hip_runtime.h>

// FixedActionDecoder: sims = (X/||x||) @ (A/||a||cols); segment-max over
// ACTION_INDEX=[0,0,0,0,1,1,1,1,1,2,3]; argmax; one-hot.
// Row-norm of X is argmax-invariant -> skipped.
//
// r7 = r4 base (passing, no-spill staging) + three riskless levers:
//  - R=4 rows/lane, 256-row wave tiles, QUARTER-row LDS phases (16 floats,
//    stride 20 dwords -> bank-balanced on write AND read): W-broadcast cost
//    halves to ~8 cyc/row, LDS pipe ~14 cyc/row << HBM 25.6. 43.8 KB/block
//    -> 3 blocks/CU = 6 waves/CU.
//  - prep fused: every block computes W from A itself (decode: f32 chunked;
//    repair: f64). No prep kernel.
//  - dynamic tile stealing (atomic counter in d_ws, hipMemsetAsync reset):
//    kills the 18% static-imbalance tail of 3906.25 tiles / 1536 waves.
//    Output is per-row pure -> deterministic regardless of assignment.
// r6 lesson enforced: NO register staging arrays (scratch spill = 250 MB
// WRITE_SIZE). Direct global->LDS, loads batched 16-deep for MLP.
// Numerics = r4: f32 pass + gap<TAU flags -> f64 repair (r1/r2-validated).
// g_bits in __device__ global (r3 lesson: never shares d_ws with data).

#define NP 11
#define TAU 1e-3f
#define QS 20  // quarter-phase row stride in dwords (16 data + 4 pad)

__device__ unsigned long long g_bits[1 << 20];  // near-tie flags, 1 bit/row

__device__ __forceinline__ void argmax_gap(const float* s, int& idx, float& gap) {
    // Segment max per ACTION_INDEX = [0,0,0,0, 1,1,1,1,1, 2, 3]
    float m0 = fmaxf(fmaxf(s[0], s[1]), fmaxf(s[2], s[3]));
    float m1 = fmaxf(fmaxf(fmaxf(s[4], s[5]), s[6]), fmaxf(s[7], s[8]));
    float m2 = s[9], m3 = s[10];
    idx = 0; float best = m0;
    if (m1 > best) { best = m1; idx = 1; }
    if (m2 > best) { best = m2; idx = 2; }
    if (m3 > best) { best = m3; idx = 3; }
    float second = -3.4e38f;
    if (idx != 0) second = fmaxf(second, m0);
    if (idx != 1) second = fmaxf(second, m1);
    if (idx != 2) second = fmaxf(second, m2);
    if (idx != 3) second = fmaxf(second, m3);
    gap = best - second;
}

__global__ __launch_bounds__(128) void decode(const float* __restrict__ X,
                                              const float* __restrict__ A,
                                              float* __restrict__ out,
                                              unsigned* __restrict__ ctr, int B) {
    __shared__ float xq[2][256][QS];  // 2 waves x 20480 B, wave-private
    __shared__ float w_lds[704];      // chunked: [(d>>2)*44 + (d&3)*11 + p]

    const int tid = threadIdx.x;
    const int lane = tid & 63;
    const int wv = tid >> 6;
    float(*buf)[QS] = xq[wv];

    // Fused prep: 11 threads normalize A's columns (f64 math, f32 store).
    if (tid < NP) {
        double ss = 0.0;
        #pragma unroll 1
        for (int d = 0; d < 64; ++d) { double v = (double)A[d * NP + tid]; ss += v * v; }
        double sc = 1.0 / fmax(sqrt(ss), 1e-8);
        #pragma unroll 1
        for (int d = 0; d < 64; ++d)
            w_lds[(d >> 2) * 44 + (d & 3) * NP + tid] =
                (float)((double)A[d * NP + tid] * sc);
    }
    __syncthreads();  // only block-wide sync; rest is wave-private

    const float4* X4 = reinterpret_cast<const float4*>(X);
    const int srow = lane >> 2;  // staging row sub-index (0..15)
    const int sf = lane & 3;     // staging float4 within quarter

    for (;;) {
        // Dynamic tile grab (1 tile = 256 rows), wave-granular.
        int t = 0;
        if (lane == 0) t = (int)atomicAdd(ctr, 1u);
        t = __builtin_amdgcn_readfirstlane(t);
        const int base = t * 256;
        if (base >= B) break;

        float acc[4][NP];
        #pragma unroll
        for (int j = 0; j < 4; ++j)
            #pragma unroll
            for (int p = 0; p < NP; ++p) acc[j][p] = 0.0f;

        #pragma unroll 1
        for (int q = 0; q < 4; ++q) {
            // Stage quarter q: 16 independent load->store pairs, no reg array.
            #pragma unroll
            for (int i = 0; i < 16; ++i) {
                int r = base + i * 16 + srow;
                if (r >= B) r = B - 1;  // tail clamp: dup read, never stored
                float4 v = X4[(size_t)r * 16 + q * 4 + sf];
                *reinterpret_cast<float4*>(&buf[i * 16 + srow][sf * 4]) = v;
            }
            __builtin_amdgcn_wave_barrier();

            // 4 chunks: 11 W-broadcast b128 + 4 lane b128 + 176 v_fma_f32.
            // unroll 1: W never bulk-hoisted (r2 lesson).
            #pragma unroll 1
            for (int kk = 0; kk < 4; ++kk) {
                const float* wrow = &w_lds[(q * 4 + kk) * 44];
                float4 x0 = *reinterpret_cast<const float4*>(&buf[lane][kk * 4]);
                float4 x1 = *reinterpret_cast<const float4*>(&buf[lane + 64][kk * 4]);
                float4 x2 = *reinterpret_cast<const float4*>(&buf[lane + 128][kk * 4]);
                float4 x3 = *reinterpret_cast<const float4*>(&buf[lane + 192][kk * 4]);
                #pragma unroll
                for (int p = 0; p < NP; ++p) {
                    float w0 = wrow[p], w1 = wrow[NP + p];
                    float w2 = wrow[2 * NP + p], w3 = wrow[3 * NP + p];
                    float u;
                    u = fmaf(x0.x, w0, acc[0][p]); u = fmaf(x0.y, w1, u);
                    u = fmaf(x0.z, w2, u);         acc[0][p] = fmaf(x0.w, w3, u);
                    u = fmaf(x1.x, w0, acc[1][p]); u = fmaf(x1.y, w1, u);
                    u = fmaf(x1.z, w2, u);         acc[1][p] = fmaf(x1.w, w3, u);
                    u = fmaf(x2.x, w0, acc[2][p]); u = fmaf(x2.y, w1, u);
                    u = fmaf(x2.z, w2, u);         acc[2][p] = fmaf(x2.w, w3, u);
                    u = fmaf(x3.x, w0, acc[3][p]); u = fmaf(x3.y, w1, u);
                    u = fmaf(x3.z, w2, u);         acc[3][p] = fmaf(x3.w, w3, u);
                }
            }
            __builtin_amdgcn_wave_barrier();
        }

        // Epilogue: argmax + flag + coalesced one-hot float4 store.
        #pragma unroll
        for (int j = 0; j < 4; ++j) {
            int idx; float gap;
            argmax_gap(acc[j], idx, gap);
            unsigned long long m = __ballot(gap < TAU);
            if (lane == 0) g_bits[t * 4 + j] = m;
            int r = base + j * 64 + lane;
            if (r < B) {
                float4 o;
                o.x = (idx == 0) ? 1.0f : 0.0f;
                o.y = (idx == 1) ? 1.0f : 0.0f;
                o.z = (idx == 2) ? 1.0f : 0.0f;
                o.w = (idx == 3) ? 1.0f : 0.0f;
                reinterpret_cast<float4*>(out)[r] = o;
            }
        }
    }
}

__global__ __launch_bounds__(256) void repair(const float* __restrict__ X,
                                              const float* __restrict__ A,
                                              float* __restrict__ out, int B) {
    __shared__ double w64[704];  // [d*11 + p]
    const int tid = threadIdx.x;
    if (tid < NP) {
        double ss = 0.0;
        #pragma unroll 1
        for (int d = 0; d < 64; ++d) { double v = (double)A[d * NP + tid]; ss += v * v; }
        double sc = 1.0 / fmax(sqrt(ss), 1e-8);
        #pragma unroll 1
        for (int d = 0; d < 64; ++d)
            w64[d * NP + tid] = (double)A[d * NP + tid] * sc;
    }
    __syncthreads();

    const int nwords = (B + 63) >> 6;
    for (int t = blockIdx.x * blockDim.x + tid; t < nwords;
         t += gridDim.x * blockDim.x) {
        unsigned long long m = g_bits[t];
        while (m) {
            int b = __builtin_ctzll(m);
            m &= m - 1;
            int row = t * 64 + b;
            if (row >= B) continue;

            double s[NP];
            #pragma unroll
            for (int p = 0; p < NP; ++p) s[p] = 0.0;
            #pragma unroll 1
            for (int d = 0; d < 64; ++d) {
                double x = (double)X[(size_t)row * 64 + d];
                #pragma unroll
                for (int p = 0; p < NP; ++p)
                    s[p] = fma(x, w64[d * NP + p], s[p]);
            }

            double m0 = fmax(fmax(s[0], s[1]), fmax(s[2], s[3]));
            double m1 = fmax(fmax(fmax(s[4], s[5]), s[6]), fmax(s[7], s[8]));
            double m2 = s[9], m3 = s[10];
            int idx = 0; double best = m0;
            if (m1 > best) { best = m1; idx = 1; }
            if (m2 > best) { best = m2; idx = 2; }
            if (m3 > best) { best = m3; idx = 3; }

            float4 o;
            o.x = (idx == 0) ? 1.0f : 0.0f;
            o.y = (idx == 1) ? 1.0f : 0.0f;
            o.z = (idx == 2) ? 1.0f : 0.0f;
            o.w = (idx == 3) ? 1.0f : 0.0f;
            reinterpret_cast<float4*>(out)[row] = o;
        }
    }
}

extern "C" void kernel_launch(void* const* d_in, const int* in_sizes, int n_in,
                              void* d_out, int out_size, void* d_ws, size_t ws_size,
                              hipStream_t stream) {
    const float* X = (const float*)d_in[0];
    const float* A = (const float*)d_in[1];
    float* out = (float*)d_out;
    const int B = in_sizes[0] / 64;

    hipMemsetAsync(d_ws, 0, 4, stream);  // tile counter reset (capture-safe)
    hipLaunchKernelGGL(decode, dim3(768), dim3(128), 0, stream,
                       X, A, out, (unsigned*)d_ws, B);
    hipLaunchKernelGGL(repair, dim3(128), dim3(256), 0, stream, X, A, out, B);
}

// Round 8
// 119.072 us; speedup vs baseline: 1.6882x; 1.2531x over previous
//
#include <hip/hip_runtime.h>

// FixedActionDecoder: sims = (X/||x||) @ (A/||a||cols); segment-max over
// ACTION_INDEX=[0,0,0,0,1,1,1,1,1,2,3]; argmax; one-hot.
// Row-norm of X is argmax-invariant -> skipped.
//
// r8 = r7 decode core (R=4, quarter-phases, 6 waves/CU) with the three r7
// overheads surgically removed:
//  - prep is a FAST PARALLEL kernel (~2us): 64 threads, LDS f64 reduction.
//    (r4/r7's serial 11-lane prep was ~15-25us; in r7 EVERY block paid it.)
//  - decode/repair COPY W from device globals into LDS (no per-block math).
//  - stealing keeps its tail-fix but loses the t=0 herd: first tile is
//    static (= wave id), atomics only for the overflow tiles.
// r6 lesson: no register staging arrays. r3 lesson: g_* never share d_ws
// (only the steal counter lives there, reset by hipMemsetAsync).
// Numerics = r4: f32 pass + gap<TAU ballot flags -> f64 repair.

#define NP 11
#define TAU 1e-3f
#define QS 20  // quarter-phase row stride in dwords (16 data + 4 pad)

__device__ __align__(16) float g_W32[704];      // [(d>>2)*44 + (d&3)*11 + p]
__device__ double g_W64[704];                   // [d*11 + p]
__device__ unsigned long long g_bits[1 << 20];  // near-tie flags, 1 bit/row

// Parallel prep: thread d owns row d of A (11 floats). Column sum-of-squares
// via LDS; 11 lanes finish norms; all 64 threads write both W copies.
__global__ void prep(const float* __restrict__ A) {
    __shared__ double sq[64][NP + 1];  // +1 pad
    __shared__ double sc[NP];
    const int d = threadIdx.x;  // 0..63
    double a[NP];
    #pragma unroll
    for (int p = 0; p < NP; ++p) {
        a[p] = (double)A[d * NP + p];
        sq[d][p] = a[p] * a[p];
    }
    __syncthreads();
    if (d < NP) {
        double ss = 0.0;
        #pragma unroll
        for (int r = 0; r < 64; ++r) ss += sq[r][d];
        sc[d] = 1.0 / fmax(sqrt(ss), 1e-8);
    }
    __syncthreads();
    #pragma unroll
    for (int p = 0; p < NP; ++p) {
        double w = a[p] * sc[p];
        g_W64[d * NP + p] = w;
        g_W32[(d >> 2) * 44 + (d & 3) * NP + p] = (float)w;
    }
}

__device__ __forceinline__ void argmax_gap(const float* s, int& idx, float& gap) {
    // Segment max per ACTION_INDEX = [0,0,0,0, 1,1,1,1,1, 2, 3]
    float m0 = fmaxf(fmaxf(s[0], s[1]), fmaxf(s[2], s[3]));
    float m1 = fmaxf(fmaxf(fmaxf(s[4], s[5]), s[6]), fmaxf(s[7], s[8]));
    float m2 = s[9], m3 = s[10];
    idx = 0; float best = m0;
    if (m1 > best) { best = m1; idx = 1; }
    if (m2 > best) { best = m2; idx = 2; }
    if (m3 > best) { best = m3; idx = 3; }
    float second = -3.4e38f;
    if (idx != 0) second = fmaxf(second, m0);
    if (idx != 1) second = fmaxf(second, m1);
    if (idx != 2) second = fmaxf(second, m2);
    if (idx != 3) second = fmaxf(second, m3);
    gap = best - second;
}

__global__ __launch_bounds__(128) void decode(const float* __restrict__ X,
                                              float* __restrict__ out,
                                              unsigned* __restrict__ ctr, int B) {
    __shared__ float xq[2][256][QS];  // 2 waves x 20480 B, wave-private
    __shared__ float w_lds[704];      // chunked copy of g_W32

    const int tid = threadIdx.x;
    const int lane = tid & 63;
    const int wv = tid >> 6;
    float(*buf)[QS] = xq[wv];

    // Copy (not compute) W into LDS: 176 float4s over 128 threads.
    for (int t = tid; t < 176; t += 128)
        reinterpret_cast<float4*>(w_lds)[t] =
            reinterpret_cast<const float4*>(g_W32)[t];
    __syncthreads();  // only block-wide sync; rest is wave-private

    const float4* X4 = reinterpret_cast<const float4*>(X);
    const int srow = lane >> 2;  // staging row sub-index (0..15)
    const int sf = lane & 3;     // staging float4 within quarter
    const int gwave = blockIdx.x * 2 + wv;
    const int nwaves = gridDim.x * 2;

    int t = gwave;  // first tile static -> no t=0 atomic herd
    for (;;) {
        const int base = t * 256;
        if (base >= B) break;

        float acc[4][NP];
        #pragma unroll
        for (int j = 0; j < 4; ++j)
            #pragma unroll
            for (int p = 0; p < NP; ++p) acc[j][p] = 0.0f;

        #pragma unroll 1
        for (int q = 0; q < 4; ++q) {
            // Stage quarter q: 16 independent load->store pairs, no reg array
            // (r6 lesson). 16 KB in flight per wave.
            #pragma unroll
            for (int i = 0; i < 16; ++i) {
                int r = base + i * 16 + srow;
                if (r >= B) r = B - 1;  // tail clamp: dup read, never stored
                float4 v = X4[(size_t)r * 16 + q * 4 + sf];
                *reinterpret_cast<float4*>(&buf[i * 16 + srow][sf * 4]) = v;
            }
            __builtin_amdgcn_wave_barrier();

            // 4 chunks: 11 W-broadcast b128 + 4 lane b128 + 176 v_fma_f32.
            // unroll 1: W never bulk-hoisted (r2 lesson).
            #pragma unroll 1
            for (int kk = 0; kk < 4; ++kk) {
                const float* wrow = &w_lds[(q * 4 + kk) * 44];
                float4 x0 = *reinterpret_cast<const float4*>(&buf[lane][kk * 4]);
                float4 x1 = *reinterpret_cast<const float4*>(&buf[lane + 64][kk * 4]);
                float4 x2 = *reinterpret_cast<const float4*>(&buf[lane + 128][kk * 4]);
                float4 x3 = *reinterpret_cast<const float4*>(&buf[lane + 192][kk * 4]);
                #pragma unroll
                for (int p = 0; p < NP; ++p) {
                    float w0 = wrow[p], w1 = wrow[NP + p];
                    float w2 = wrow[2 * NP + p], w3 = wrow[3 * NP + p];
                    float u;
                    u = fmaf(x0.x, w0, acc[0][p]); u = fmaf(x0.y, w1, u);
                    u = fmaf(x0.z, w2, u);         acc[0][p] = fmaf(x0.w, w3, u);
                    u = fmaf(x1.x, w0, acc[1][p]); u = fmaf(x1.y, w1, u);
                    u = fmaf(x1.z, w2, u);         acc[1][p] = fmaf(x1.w, w3, u);
                    u = fmaf(x2.x, w0, acc[2][p]); u = fmaf(x2.y, w1, u);
                    u = fmaf(x2.z, w2, u);         acc[2][p] = fmaf(x2.w, w3, u);
                    u = fmaf(x3.x, w0, acc[3][p]); u = fmaf(x3.y, w1, u);
                    u = fmaf(x3.z, w2, u);         acc[3][p] = fmaf(x3.w, w3, u);
                }
            }
            __builtin_amdgcn_wave_barrier();
        }

        // Epilogue: argmax + flag + coalesced one-hot float4 store.
        #pragma unroll
        for (int j = 0; j < 4; ++j) {
            int idx; float gap;
            argmax_gap(acc[j], idx, gap);
            unsigned long long m = __ballot(gap < TAU);
            if (lane == 0) g_bits[t * 4 + j] = m;
            int r = base + j * 64 + lane;
            if (r < B) {
                float4 o;
                o.x = (idx == 0) ? 1.0f : 0.0f;
                o.y = (idx == 1) ? 1.0f : 0.0f;
                o.z = (idx == 2) ? 1.0f : 0.0f;
                o.w = (idx == 3) ? 1.0f : 0.0f;
                reinterpret_cast<float4*>(out)[r] = o;
            }
        }

        // Steal next tile (overflow range only; spread in time).
        int nt = 0;
        if (lane == 0) nt = (int)atomicAdd(ctr, 1u);
        t = __builtin_amdgcn_readfirstlane(nt) + nwaves;
    }
}

__global__ __launch_bounds__(256) void repair(const float* __restrict__ X,
                                              float* __restrict__ out, int B) {
    __shared__ double w64[704];  // copy of g_W64
    const int tid = threadIdx.x;
    for (int i = tid; i < 704; i += 256) w64[i] = g_W64[i];
    __syncthreads();

    const int nwords = (B + 63) >> 6;
    for (int t = blockIdx.x * blockDim.x + tid; t < nwords;
         t += gridDim.x * blockDim.x) {
        unsigned long long m = g_bits[t];
        while (m) {
            int b = __builtin_ctzll(m);
            m &= m - 1;
            int row = t * 64 + b;
            if (row >= B) continue;

            double s[NP];
            #pragma unroll
            for (int p = 0; p < NP; ++p) s[p] = 0.0;
            #pragma unroll 1
            for (int d = 0; d < 64; ++d) {
                double x = (double)X[(size_t)row * 64 + d];
                #pragma unroll
                for (int p = 0; p < NP; ++p)
                    s[p] = fma(x, w64[d * NP + p], s[p]);
            }

            double m0 = fmax(fmax(s[0], s[1]), fmax(s[2], s[3]));
            double m1 = fmax(fmax(fmax(s[4], s[5]), s[6]), fmax(s[7], s[8]));
            double m2 = s[9], m3 = s[10];
            int idx = 0; double best = m0;
            if (m1 > best) { best = m1; idx = 1; }
            if (m2 > best) { best = m2; idx = 2; }
            if (m3 > best) { best = m3; idx = 3; }

            float4 o;
            o.x = (idx == 0) ? 1.0f : 0.0f;
            o.y = (idx == 1) ? 1.0f : 0.0f;
            o.z = (idx == 2) ? 1.0f : 0.0f;
            o.w = (idx == 3) ? 1.0f : 0.0f;
            reinterpret_cast<float4*>(out)[row] = o;
        }
    }
}

extern "C" void kernel_launch(void* const* d_in, const int* in_sizes, int n_in,
                              void* d_out, int out_size, void* d_ws, size_t ws_size,
                              hipStream_t stream) {
    const float* X = (const float*)d_in[0];
    const float* A = (const float*)d_in[1];
    float* out = (float*)d_out;
    const int B = in_sizes[0] / 64;

    hipMemsetAsync(d_ws, 0, 4, stream);  // steal counter reset (capture-safe)
    hipLaunchKernelGGL(prep, dim3(1), dim3(64), 0, stream, A);
    hipLaunchKernelGGL(decode, dim3(768), dim3(128), 0, stream,
                       X, out, (unsigned*)d_ws, B);
    hipLaunchKernelGGL(repair, dim3(128), dim3(256), 0, stream, X, out, B);
}

// Round 9
// 77.828 us; speedup vs baseline: 2.5829x; 1.5299x over previous
//
#include <hip/hip_runtime.h>

// FixedActionDecoder: sims = (X/||x||) @ (A/||a||cols); segment-max over
// ACTION_INDEX=[0,0,0,0,1,1,1,1,1,2,3]; argmax; one-hot.
// Row-norm of X is argmax-invariant -> skipped.
//
// r9 = consolidation of proven-best pieces:
//  - decode: r4's VERBATIM structure (the best measured: half-row phases,
//    8 lanes/row -> each staging request covers a full 128B line; 128-row
//    tiles, 2 rows/lane, stride-36 LDS rows, 4 blocks/CU = 8 waves/CU).
//    r6/r7/r8's quarter-phases split lines -> 28% over-fetch -> reverted.
//    One layout-only tweak: W stored as d-major QUADS per chunk so the
//    broadcast is 11 uniform ds_read_b128 per chunk (never 44 b32).
//  - prep: r8's parallel version (~2us; r4's serial one was ~20us and was
//    most of the r4-total overhead).
//  - repair: r8's version (W64 via LDS copy, not per-row global loads).
// r6 lesson: no register staging arrays. r3 lesson: g_* never in d_ws.
// Numerics = r4: f32 pass + gap<TAU ballot flags -> f64 repair
// (r1/r2-validated f64 path; exact match in all passing rounds).

#define NP 11
#define TAU 1e-3f
#define LROW 36  // LDS row stride (dwords): 32 data + 4 pad (r4-verified)

__device__ __align__(16) float g_W32[704];      // [(d>>2)*44 + p*4 + (d&3)]
__device__ double g_W64[704];                   // [d*11 + p]
__device__ unsigned long long g_bits[1 << 20];  // near-tie flags, 1 bit/row

// Parallel prep: thread d owns row d of A (11 floats). Column sum-of-squares
// via LDS; 11 lanes finish norms; all 64 threads write both W copies.
__global__ void prep(const float* __restrict__ A) {
    __shared__ double sq[64][NP + 1];  // +1 pad
    __shared__ double sc[NP];
    const int d = threadIdx.x;  // 0..63
    double a[NP];
    #pragma unroll
    for (int p = 0; p < NP; ++p) {
        a[p] = (double)A[d * NP + p];
        sq[d][p] = a[p] * a[p];
    }
    __syncthreads();
    if (d < NP) {
        double ss = 0.0;
        #pragma unroll
        for (int r = 0; r < 64; ++r) ss += sq[r][d];
        sc[d] = 1.0 / fmax(sqrt(ss), 1e-8);
    }
    __syncthreads();
    #pragma unroll
    for (int p = 0; p < NP; ++p) {
        double w = a[p] * sc[p];
        g_W64[d * NP + p] = w;
        g_W32[(d >> 2) * 44 + p * 4 + (d & 3)] = (float)w;  // d-major quad
    }
}

__device__ __forceinline__ void argmax_gap(const float* s, int& idx, float& gap) {
    // Segment max per ACTION_INDEX = [0,0,0,0, 1,1,1,1,1, 2, 3]
    float m0 = fmaxf(fmaxf(s[0], s[1]), fmaxf(s[2], s[3]));
    float m1 = fmaxf(fmaxf(fmaxf(s[4], s[5]), s[6]), fmaxf(s[7], s[8]));
    float m2 = s[9], m3 = s[10];
    idx = 0; float best = m0;
    if (m1 > best) { best = m1; idx = 1; }
    if (m2 > best) { best = m2; idx = 2; }
    if (m3 > best) { best = m3; idx = 3; }
    float second = -3.4e38f;
    if (idx != 0) second = fmaxf(second, m0);
    if (idx != 1) second = fmaxf(second, m1);
    if (idx != 2) second = fmaxf(second, m2);
    if (idx != 3) second = fmaxf(second, m3);
    gap = best - second;
}

__global__ __launch_bounds__(128) void decode(const float* __restrict__ X,
                                              float* __restrict__ out, int B) {
    __shared__ float xbuf[2][128][LROW];  // 36864 B, wave-private halves
    __shared__ float w_lds[704];          // 2816 B; total 39680 -> 4 blk/CU

    const int tid = threadIdx.x;
    const int lane = tid & 63;
    const int wv = tid >> 6;
    float(*buf)[LROW] = xbuf[wv];

    // Copy W into LDS: 176 float4s over 128 threads.
    for (int t = tid; t < 176; t += 128)
        reinterpret_cast<float4*>(w_lds)[t] =
            reinterpret_cast<const float4*>(g_W32)[t];
    __syncthreads();  // only block-wide sync; rest is wave-private

    const float4* X4 = reinterpret_cast<const float4*>(X);
    const int gwave = blockIdx.x * 2 + wv;
    const int nwaves = gridDim.x * 2;

    #pragma unroll 1
    for (int base = gwave * 128; base < B; base += nwaves * 128) {
        float acc0[NP], acc1[NP];
        #pragma unroll
        for (int p = 0; p < NP; ++p) { acc0[p] = 0.0f; acc1[p] = 0.0f; }

        #pragma unroll
        for (int st = 0; st < 2; ++st) {  // d half: st*32 .. st*32+31
            // Stage 128 rows x 32 floats; instr i covers 8 FULL 128B lines
            // (8 lanes/row x 16 B contiguous). r4-exact.
            #pragma unroll
            for (int i = 0; i < 16; ++i) {
                int fid = i * 64 + lane;  // 0..1023
                int row = fid >> 3;       // 0..127
                int f = fid & 7;          // 0..7
                int r = base + row;
                if (r >= B) r = B - 1;    // tail clamp (dup read, harmless)
                float4 v = X4[(size_t)r * 16 + st * 8 + f];
                *reinterpret_cast<float4*>(&buf[row][f * 4]) = v;
            }
            __builtin_amdgcn_wave_barrier();  // wave-private buf: fence only

            // Per 4-d chunk: 2 lane b128 (X rows) + 11 uniform b128 (W
            // quads) + 88 v_fma_f32. unroll 1: W never bulk-hoisted (r2).
            #pragma unroll 1
            for (int kk = 0; kk < 8; ++kk) {
                const float* wrow = &w_lds[(st * 8 + kk) * 44];
                float4 x0 = *reinterpret_cast<const float4*>(&buf[lane][kk * 4]);
                float4 x1 = *reinterpret_cast<const float4*>(&buf[lane + 64][kk * 4]);
                #pragma unroll
                for (int p = 0; p < NP; ++p) {
                    float4 wq = *reinterpret_cast<const float4*>(&wrow[p * 4]);
                    float t0 = fmaf(x0.x, wq.x, acc0[p]);
                    t0 = fmaf(x0.y, wq.y, t0);
                    t0 = fmaf(x0.z, wq.z, t0);
                    acc0[p] = fmaf(x0.w, wq.w, t0);
                    float t1 = fmaf(x1.x, wq.x, acc1[p]);
                    t1 = fmaf(x1.y, wq.y, t1);
                    t1 = fmaf(x1.z, wq.z, t1);
                    acc1[p] = fmaf(x1.w, wq.w, t1);
                }
            }
            __builtin_amdgcn_wave_barrier();
        }

        int idx0, idx1; float gap0, gap1;
        argmax_gap(acc0, idx0, gap0);
        argmax_gap(acc1, idx1, gap1);

        unsigned long long m0 = __ballot(gap0 < TAU);
        unsigned long long m1 = __ballot(gap1 < TAU);
        if (lane == 0) {
            g_bits[(base >> 6) + 0] = m0;
            g_bits[(base >> 6) + 1] = m1;
        }

        int r0 = base + lane, r1 = base + 64 + lane;
        if (r0 < B) {
            float4 o;
            o.x = (idx0 == 0) ? 1.0f : 0.0f;
            o.y = (idx0 == 1) ? 1.0f : 0.0f;
            o.z = (idx0 == 2) ? 1.0f : 0.0f;
            o.w = (idx0 == 3) ? 1.0f : 0.0f;
            reinterpret_cast<float4*>(out)[r0] = o;
        }
        if (r1 < B) {
            float4 o;
            o.x = (idx1 == 0) ? 1.0f : 0.0f;
            o.y = (idx1 == 1) ? 1.0f : 0.0f;
            o.z = (idx1 == 2) ? 1.0f : 0.0f;
            o.w = (idx1 == 3) ? 1.0f : 0.0f;
            reinterpret_cast<float4*>(out)[r1] = o;
        }
    }
}

__global__ __launch_bounds__(256) void repair(const float* __restrict__ X,
                                              float* __restrict__ out, int B) {
    __shared__ double w64[704];  // copy of g_W64
    const int tid = threadIdx.x;
    for (int i = tid; i < 704; i += 256) w64[i] = g_W64[i];
    __syncthreads();

    const int nwords = (B + 63) >> 6;
    for (int t = blockIdx.x * blockDim.x + tid; t < nwords;
         t += gridDim.x * blockDim.x) {
        unsigned long long m = g_bits[t];
        while (m) {
            int b = __builtin_ctzll(m);
            m &= m - 1;
            int row = t * 64 + b;
            if (row >= B) continue;

            double s[NP];
            #pragma unroll
            for (int p = 0; p < NP; ++p) s[p] = 0.0;
            #pragma unroll 1
            for (int d = 0; d < 64; ++d) {
                double x = (double)X[(size_t)row * 64 + d];
                #pragma unroll
                for (int p = 0; p < NP; ++p)
                    s[p] = fma(x, w64[d * NP + p], s[p]);
            }

            double m0 = fmax(fmax(s[0], s[1]), fmax(s[2], s[3]));
            double m1 = fmax(fmax(fmax(s[4], s[5]), s[6]), fmax(s[7], s[8]));
            double m2 = s[9], m3 = s[10];
            int idx = 0; double best = m0;
            if (m1 > best) { best = m1; idx = 1; }
            if (m2 > best) { best = m2; idx = 2; }
            if (m3 > best) { best = m3; idx = 3; }

            float4 o;
            o.x = (idx == 0) ? 1.0f : 0.0f;
            o.y = (idx == 1) ? 1.0f : 0.0f;
            o.z = (idx == 2) ? 1.0f : 0.0f;
            o.w = (idx == 3) ? 1.0f : 0.0f;
            reinterpret_cast<float4*>(out)[row] = o;
        }
    }
}

extern "C" void kernel_launch(void* const* d_in, const int* in_sizes, int n_in,
                              void* d_out, int out_size, void* d_ws, size_t ws_size,
                              hipStream_t stream) {
    const float* X = (const float*)d_in[0];
    const float* A = (const float*)d_in[1];
    float* out = (float*)d_out;
    const int B = in_sizes[0] / 64;

    hipLaunchKernelGGL(prep, dim3(1), dim3(64), 0, stream, A);
    hipLaunchKernelGGL(decode, dim3(1024), dim3(128), 0, stream, X, out, B);
    hipLaunchKernelGGL(repair, dim3(128), dim3(256), 0, stream, X, out, B);
}